// Round 8
// baseline (515.030 us; speedup 1.0000x reference)
//
#include <hip/hip_runtime.h>
#include <math.h>

// Problem constants
#define NN   2048
#define EE   8192
#define CNF  256
#define MN   16384
#define ME   65536
#define KK   1024

// Output layout (float element offsets)
#define OUT_XN   ((size_t)0)
#define OUT_L0   ((size_t)262144)
#define OUT_XE   ((size_t)1310720)
#define OUT_L1   ((size_t)3407872)
#define OUT_PM   ((size_t)70516736)
#define OUT_XN0  ((size_t)78905344)
#define OUT_XE0  ((size_t)79167488)

// Workspace layout (element offsets)
#define WS_T1N    0
#define WS_SLINN  2048
#define WS_T1E    4096
#define WS_SLINE  12288
#define WS_SCN    20480
#define WS_SCE    22528
#define WS_AGGN   32768
#define WS_AGGE   34816
#define WS_LAM    43008
#define WS_IDXK   43520
#define WS_RANK   44544
#define WS_OFFS   47616
#define WS_ADJE   66176   // int[16384]
#define WS_KEEPE  82560   // int[8192]
#define WS_FLAG1  90752   // chain: scores/ranks/keep ready
#define WS_FLAG2  90753   // chain: lam/offs/adje ready

#define DCAP  8
#define PWR_T 96
#define RBAD  0xFFFFu

// =====================================================================
// Kernel A: row dots (wave per row) + zero accumulators AND flags.
// =====================================================================
__global__ void k_prep(const float* __restrict__ xn, const float* __restrict__ xe,
                       const float* __restrict__ Wn0, const float* __restrict__ Wn1,
                       const float* __restrict__ We0, const float* __restrict__ We1,
                       float* __restrict__ wsf, int* __restrict__ wsi) {
    if (blockIdx.x == 0) {   // zero accumulators + producer-consumer flags
        for (int i = threadIdx.x; i < 2048; i += 256) wsf[WS_AGGN + i] = 0.f;
        for (int i = threadIdx.x; i < 8192; i += 256) wsf[WS_AGGE + i] = 0.f;
        if (threadIdx.x == 0) { wsi[WS_FLAG1] = 0; wsi[WS_FLAG2] = 0; }
    }
    int gw = (blockIdx.x * blockDim.x + threadIdx.x) >> 6;
    int lane = threadIdx.x & 63;
    int wstr = (gridDim.x * blockDim.x) >> 6;
    for (int row = gw; row < NN + EE; row += wstr) {
        const float *x, *W0, *W1; float *t1, *sl; int r;
        if (row < NN) { r = row;      x = xn + (size_t)r * CNF; W0 = Wn0; W1 = Wn1; t1 = wsf + WS_T1N; sl = wsf + WS_SLINN; }
        else          { r = row - NN; x = xe + (size_t)r * CNF; W0 = We0; W1 = We1; t1 = wsf + WS_T1E; sl = wsf + WS_SLINE; }
        float4 xv = ((const float4*)x)[lane];
        float4 w0 = ((const float4*)W0)[lane];
        float4 w1 = ((const float4*)W1)[lane];
        float d0 = xv.x*w0.x + xv.y*w0.y + xv.z*w0.z + xv.w*w0.w;
        float d1 = xv.x*w1.x + xv.y*w1.y + xv.z*w1.z + xv.w*w1.w;
        #pragma unroll
        for (int o = 32; o > 0; o >>= 1) { d0 += __shfl_down(d0, o, 64); d1 += __shfl_down(d1, o, 64); }
        if (lane == 0) { t1[r] = d1; sl[r] = d0 + d1; }
    }
}

// =====================================================================
// Kernel B: conv-edge scatter, grid-wide.
// =====================================================================
__global__ void k_agg(const int* __restrict__ ein, const float* __restrict__ ewn,
                      const int* __restrict__ eie, const float* __restrict__ ewe,
                      float* __restrict__ wsf) {
    int i = blockIdx.x * blockDim.x + threadIdx.x;
    if (i < MN) {
        int s = ein[i], d = ein[MN + i];
        atomicAdd(wsf + WS_AGGN + d, ewn[i] * wsf[WS_T1N + s]);
    }
    if (i < ME) {
        int s = eie[i], d = eie[ME + i];
        atomicAdd(wsf + WS_AGGE + d, ewe[i] * wsf[WS_T1E + s]);
    }
}

// --------------------------------------------------- block reduce (16 waves)
__device__ __forceinline__ float block_reduce_sum(float val, float* red) {
    #pragma unroll
    for (int o = 32; o > 0; o >>= 1) val += __shfl_down(val, o, 64);
    int lane = threadIdx.x & 63, wid = threadIdx.x >> 6;
    if (lane == 0) red[wid] = val;
    __syncthreads();
    float r = 0.0f;
    if (threadIdx.x < 16) {
        r = red[threadIdx.x];
        #pragma unroll
        for (int o = 8; o > 0; o >>= 1) r += __shfl_down(r, o, 16);
        if (threadIdx.x == 0) red[0] = r;
    }
    __syncthreads();
    float out = red[0];
    __syncthreads();
    return out;
}

__device__ __forceinline__ void wait_flag(int* f) {
    if (threadIdx.x == 0) {
        while (__hip_atomic_load(f, __ATOMIC_ACQUIRE, __HIP_MEMORY_SCOPE_AGENT) == 0)
            __builtin_amdgcn_s_sleep(8);
    }
    __syncthreads();
}

__device__ __forceinline__ void set_flag(int* f) {
    __syncthreads();   // all block-0 stores drained (vmcnt(0)) before release
    if (threadIdx.x == 0)
        __hip_atomic_store(f, 1, __ATOMIC_RELEASE, __HIP_MEMORY_SCOPE_AGENT);
}

// =====================================================================
// Kernel C (fused mid+final): block 0 = LDS-resident serial chain,
// releasing two one-way flags; blocks 1..255 = zero L0/L1/PM (306 MB),
// then after flag1 write features (36 MB), after flag2 do scatters.
// One-way release/acquire flags (no RMW contention; R4's countdown
// barriers cost ~200us, this costs ~1us). 256 blocks all co-resident.
// =====================================================================
__global__ __launch_bounds__(1024) void k_mid(
        const int* __restrict__ ei,
        const float* __restrict__ bn, const float* __restrict__ be,
        const float* __restrict__ xn, const float* __restrict__ xe,
        const float* __restrict__ xn0, const float* __restrict__ xe0,
        float* __restrict__ out, float* __restrict__ wsf, int* __restrict__ wsi) {
    int tid = threadIdx.x, bid = blockIdx.x;
    __shared__ unsigned long long s_u64[2048];       // 16 KB (chain scratch)
    __shared__ float s_joint[2048];                  // 8 KB
    __shared__ unsigned short s_rank[2048];          // 4 KB
    __shared__ unsigned short s_adjo[16384 + DCAP];  // 32 KB
    __shared__ float s_red[16];
    int* s_i = (int*)s_u64;

    if (bid != 0) {
        // ---------------- consumers: zero sparse output regions ----------------
        size_t w = (size_t)(bid - 1) * 1024 + tid;
        size_t ws = (size_t)(gridDim.x - 1) * 1024;
        float4 z = make_float4(0.f, 0.f, 0.f, 0.f);
        float4* l1 = (float4*)(out + OUT_L1);
        for (size_t p = w; p < (size_t)EE * EE / 4; p += ws) l1[p] = z;
        float4* pm = (float4*)(out + OUT_PM);
        for (size_t p = w; p < (size_t)KK * EE / 4; p += ws) pm[p] = z;
        float4* l0 = (float4*)(out + OUT_L0);
        for (size_t p = w; p < (size_t)KK * KK / 4; p += ws) l0[p] = z;

        // ---------------- stage 1: feature outputs (need scores/ranks/keep) ----
        wait_flag(wsi + WS_FLAG1);
        int gt = (int)w, gstr = (int)ws;
        for (int i = gt; i < KK * 64; i += gstr) {       // kept-node gathers
            int r = i >> 6, c = i & 63;
            int src = wsi[WS_IDXK + r];
            float s = wsf[WS_SCN + src];
            float4 v = ((const float4*)(xn + (size_t)src * CNF))[c];
            v.x *= s; v.y *= s; v.z *= s; v.w *= s;
            ((float4*)(out + OUT_XN))[(size_t)r * 64 + c] = v;
            ((float4*)(out + OUT_XN0))[(size_t)r * 64 + c] = ((const float4*)(xn0 + (size_t)src * CNF))[c];
        }
        for (int i = gt; i < EE * 64; i += gstr) {       // edge rows, dense
            int e = i >> 6, c = i & 63;
            float m = wsi[WS_KEEPE + e] ? 1.0f : 0.0f;
            float s = m * wsf[WS_SCE + e];
            float4 v = ((const float4*)(xe + (size_t)e * CNF))[c];
            v.x *= s; v.y *= s; v.z *= s; v.w *= s;
            ((float4*)(out + OUT_XE))[(size_t)e * 64 + c] = v;
            float4 v0 = ((const float4*)(xe0 + (size_t)e * CNF))[c];
            v0.x *= m; v0.y *= m; v0.z *= m; v0.w *= m;
            ((float4*)(out + OUT_XE0))[(size_t)e * 64 + c] = v0;
        }

        // ---------------- stage 2: lam-dependent scatters ----------------------
        wait_flag(wsi + WS_FLAG2);
        float sc = 2.0f / wsf[WS_LAM];
        {   // par_masked + L0
            float* pmf = out + OUT_PM;
            float* L0 = out + OUT_L0;
            for (int e = gt; e < EE; e += gstr) {
                int s = ei[e], d = ei[EE + e];
                int rs = wsi[WS_RANK + s], rd = wsi[WS_RANK + d];
                if (rs < 0 || rd < 0 || s == d) continue;
                pmf[(size_t)rs * EE + e] = -1.0f;
                pmf[(size_t)rd * EE + e] =  1.0f;
                atomicAdd(&L0[(size_t)rs * KK + rs],  sc);
                atomicAdd(&L0[(size_t)rd * KK + rd],  sc);
                atomicAdd(&L0[(size_t)rs * KK + rd], -sc);
                atomicAdd(&L0[(size_t)rd * KK + rs], -sc);
            }
        }
        {   // L1: wave per node-row
            float* L1 = out + OUT_L1;
            int gwv = gt >> 6, lane = gt & 63, wstr2 = gstr >> 6;
            for (int r = gwv; r < KK; r += wstr2) {
                int o0 = wsi[WS_OFFS + r], o1 = wsi[WS_OFFS + r + 1];
                for (int i = o0; i < o1; ++i) {
                    int eiv = wsi[WS_ADJE + i];
                    int e = eiv >> 1;
                    float si = (eiv & 1) ? sc : -sc;
                    for (int j = o0 + lane; j < o1; j += 64) {
                        int ejv = wsi[WS_ADJE + j];
                        atomicAdd(&L1[(size_t)e * EE + (ejv >> 1)], (ejv & 1) ? si : -si);
                    }
                }
            }
        }
        return;
    }

    // ==================== block 0: serial chain (LDS-resident) ====================
    // P3: sigmoid scores
    float bnv = bn[0], bev = be[0];
    for (int i = tid; i < NN; i += 1024) {
        float zv = wsf[WS_SLINN + i] - wsf[WS_AGGN + i] + bnv;
        float s = 1.0f / (1.0f + expf(-zv));
        wsf[WS_SCN + i] = s;
        s_joint[i] = s;
    }
    for (int j = tid; j < EE; j += 1024) {
        float zv = wsf[WS_SLINE + j] - wsf[WS_AGGE + j] + bev;
        wsf[WS_SCE + j] = 1.0f / (1.0f + expf(-zv));
    }
    __syncthreads();

    // P4: joint node score (LDS atomics)
    for (int e = tid; e < EE; e += 1024) {
        float v = 0.125f * wsf[WS_SCE + e];
        atomicAdd(&s_joint[ei[e]], v);
        atomicAdd(&s_joint[ei[EE + e]], v);
    }
    __syncthreads();

    // P5: top-K: bitonic sort 2048 (val,idx) u64 desc, then flag+scan ranks
    for (int i = tid; i < 2048; i += 1024) {
        float f = s_joint[i];
        unsigned u = __float_as_uint(f);
        unsigned sk = (u & 0x80000000u) ? ~u : (u | 0x80000000u);
        s_u64[i] = (((unsigned long long)(~sk)) << 32) | (unsigned)i;
    }
    __syncthreads();
    for (int k = 2; k <= 2048; k <<= 1) {
        for (int j = k >> 1; j >= 1; j >>= 1) {
            for (int i = tid; i < 2048; i += 1024) {
                int ixj = i ^ j;
                if (ixj > i) {
                    bool up = ((i & k) == 0);
                    unsigned long long a = s_u64[i], b = s_u64[ixj];
                    if ((a > b) == up) { s_u64[i] = b; s_u64[ixj] = a; }
                }
            }
            __syncthreads();
        }
    }
    int myid = (int)(s_u64[tid] & 0xFFFFFFFFu);
    __syncthreads();
    {
        s_i[tid] = 0; s_i[tid + 1024] = 0; s_i[tid + 2048] = 0;
        __syncthreads();
        s_i[myid] = 1;
        __syncthreads();
        int a0 = s_i[2 * tid], a1 = s_i[2 * tid + 1];
        int pairsum = a0 + a1;
        s_i[2048 + tid] = pairsum;
        __syncthreads();
        for (int off = 1; off < 1024; off <<= 1) {
            int v = (tid >= off) ? s_i[2048 + tid - off] : 0;
            __syncthreads();
            s_i[2048 + tid] += v;
            __syncthreads();
        }
        int excl = s_i[2048 + tid] - pairsum;
        int i0 = 2 * tid, i1 = 2 * tid + 1;
        int r0 = excl, r1 = excl + a0;
        s_rank[i0] = a0 ? (unsigned short)r0 : (unsigned short)RBAD;
        s_rank[i1] = a1 ? (unsigned short)r1 : (unsigned short)RBAD;
        wsi[WS_RANK + i0] = a0 ? r0 : -1;
        wsi[WS_RANK + i1] = a1 ? r1 : -1;
        if (a0) wsi[WS_IDXK + r0] = i0;
        if (a1) wsi[WS_IDXK + r1] = i1;
    }
    __syncthreads();

    // P6: degrees (LDS) + keep_e flags (global, for consumers)
    s_i[tid] = 0;
    __syncthreads();
    for (int e = tid; e < EE; e += 1024) {
        int s = ei[e], d = ei[EE + e];
        unsigned rs = s_rank[s], rd = s_rank[d];
        int kept = (rs != RBAD && rd != RBAD);
        wsi[WS_KEEPE + e] = kept;
        if (kept && s != d) {
            atomicAdd(&s_i[(int)rs], 1);
            atomicAdd(&s_i[(int)rd], 1);
        }
    }
    set_flag(wsi + WS_FLAG1);   // scores/ranks/idxk/keep visible -> features can go
    __syncthreads();

    // P7: CSR offsets
    {
        int dg = s_i[tid];
        s_i[1024 + tid] = dg;
        for (int off = 1; off < 1024; off <<= 1) {
            __syncthreads();
            int v = (tid >= off) ? s_i[1024 + tid - off] : 0;
            __syncthreads();
            s_i[1024 + tid] += v;
        }
        __syncthreads();
        int offs = s_i[1024 + tid] - dg;
        s_i[2048 + tid] = offs;
        wsi[WS_OFFS + tid] = offs;
        if (tid == 1023) wsi[WS_OFFS + 1024] = s_i[1024 + 1023];
    }
    __syncthreads();

    // P8: CSR fill (adjo -> LDS for power; adje -> global for consumers)
    for (int e = tid; e < EE; e += 1024) {
        int s = ei[e], d = ei[EE + e];
        unsigned rs = s_rank[s], rd = s_rank[d];
        if (rs != RBAD && rd != RBAD && s != d) {
            int p = atomicAdd(&s_i[2048 + (int)rs], 1);
            s_adjo[p] = (unsigned short)rd;
            wsi[WS_ADJE + p] = (e << 1);
            int q = atomicAdd(&s_i[2048 + (int)rd], 1);
            s_adjo[q] = (unsigned short)rs;
            wsi[WS_ADJE + q] = (e << 1) | 1;
        }
    }
    __syncthreads();

    // P9: power iteration for lambda_max (v aliases s_i; offs from global first)
    {
        int o0 = wsi[WS_OFFS + tid];
        int d  = wsi[WS_OFFS + tid + 1] - o0;
        __syncthreads();
        float* v0 = (float*)s_u64;
        float* v1 = v0 + 1024;
        unsigned h = (unsigned)tid * 2654435761u + 911u;
        h ^= h >> 15; h *= 2246822519u; h ^= h >> 13;
        v0[tid] = (float)(h & 0xFFFFu) * (1.0f / 65536.0f) - 0.5f;
        int aj[DCAP];
        #pragma unroll
        for (int j = 0; j < DCAP; ++j) aj[j] = (j < d) ? (int)s_adjo[o0 + j] : 0;
        __syncthreads();
        float* vc = v0; float* vn = v1;
        for (int iter = 0; iter < PWR_T; ++iter) {
            float acc = 0.0f;
            #pragma unroll
            for (int j = 0; j < DCAP; ++j) acc += (j < d) ? vc[aj[j]] : 0.0f;
            for (int i = o0 + DCAP; i < o0 + d; ++i) acc += vc[(int)s_adjo[i]];
            float y = (float)d * vc[tid] - acc;
            if ((iter & 7) == 7) {
                float n2 = block_reduce_sum(y * y, s_red);
                y *= (n2 > 0.0f) ? rsqrtf(n2) : 0.0f;
            }
            vn[tid] = y;
            __syncthreads();
            float* tmp = vc; vc = vn; vn = tmp;
        }
        float acc = 0.0f;
        #pragma unroll
        for (int j = 0; j < DCAP; ++j) acc += (j < d) ? vc[aj[j]] : 0.0f;
        for (int i = o0 + DCAP; i < o0 + d; ++i) acc += vc[(int)s_adjo[i]];
        float y = (float)d * vc[tid] - acc;
        float rq = block_reduce_sum(vc[tid] * y, s_red);
        if (tid == 0) wsf[WS_LAM] = rq;
    }
    set_flag(wsi + WS_FLAG2);   // lam/offs/adje visible -> scatters can go
}

extern "C" void kernel_launch(void* const* d_in, const int* in_sizes, int n_in,
                              void* d_out, int out_size, void* d_ws, size_t ws_size,
                              hipStream_t stream) {
    const float* x_n  = (const float*)d_in[0];
    const int*   ei_n = (const int*)  d_in[1];
    const float* ew_n = (const float*)d_in[2];
    const float* x_e  = (const float*)d_in[3];
    const int*   ei_e = (const int*)  d_in[4];
    const float* ew_e = (const float*)d_in[5];
    const int*   ei   = (const int*)  d_in[6];
    const float* x_n0 = (const float*)d_in[9];
    const float* x_e0 = (const float*)d_in[10];
    const float* Wn0  = (const float*)d_in[11];
    const float* Wn1  = (const float*)d_in[12];
    const float* bn   = (const float*)d_in[13];
    const float* We0  = (const float*)d_in[14];
    const float* We1  = (const float*)d_in[15];
    const float* be   = (const float*)d_in[16];

    float* out = (float*)d_out;
    float* wsf = (float*)d_ws;
    int*   wsi = (int*)d_ws;

    k_prep<<<640, 256, 0, stream>>>(x_n, x_e, Wn0, Wn1, We0, We1, wsf, wsi);
    k_agg <<<256, 256, 0, stream>>>(ei_n, ew_n, ei_e, ew_e, wsf);
    k_mid <<<256, 1024, 0, stream>>>(ei, bn, be, x_n, x_e, x_n0, x_e0, out, wsf, wsi);
}

// Round 10
// 474.958 us; speedup vs baseline: 1.0844x; 1.0844x over previous
//
#include <hip/hip_runtime.h>
#include <math.h>

// Problem constants
#define NN   2048
#define EE   8192
#define CNF  256
#define MN   16384
#define ME   65536
#define KK   1024

// Output layout (float element offsets)
#define OUT_XN   ((size_t)0)
#define OUT_L0   ((size_t)262144)
#define OUT_XE   ((size_t)1310720)
#define OUT_L1   ((size_t)3407872)
#define OUT_PM   ((size_t)70516736)
#define OUT_XN0  ((size_t)78905344)
#define OUT_XE0  ((size_t)79167488)

// Workspace layout (element offsets)
#define WS_T1N    0
#define WS_SLINN  2048
#define WS_T1E    4096
#define WS_SLINE  12288
#define WS_SCN    20480
#define WS_SCE    22528
#define WS_AGGN   32768
#define WS_AGGE   34816
#define WS_LAM    43008
#define WS_IDXK   43520
#define WS_RANK   44544
#define WS_OFFS   47616
#define WS_ADJE   66176   // int[16384]
#define WS_KEEPE  82560   // int[8192]

#define DCAP  8
#define PWR_T 64          // 96->64: Rayleigh error (lam_i/lam_1)^128-weighted, ~1e-4 rel
#define RBAD  0xFFFFu

// native vector for nontemporal builtin (HIP float4 is a class -> rejected)
typedef float vf4 __attribute__((ext_vector_type(4)));

// =====================================================================
// Kernel A: row dots (wave per row) + zero the ws accumulators.
// =====================================================================
__global__ void k_prep(const float* __restrict__ xn, const float* __restrict__ xe,
                       const float* __restrict__ Wn0, const float* __restrict__ Wn1,
                       const float* __restrict__ We0, const float* __restrict__ We1,
                       float* __restrict__ wsf) {
    if (blockIdx.x == 0) {   // zero accumulators (AGGN, AGGE)
        for (int i = threadIdx.x; i < 2048; i += 256) wsf[WS_AGGN + i] = 0.f;
        for (int i = threadIdx.x; i < 8192; i += 256) wsf[WS_AGGE + i] = 0.f;
    }
    int gw = (blockIdx.x * blockDim.x + threadIdx.x) >> 6;
    int lane = threadIdx.x & 63;
    int wstr = (gridDim.x * blockDim.x) >> 6;
    for (int row = gw; row < NN + EE; row += wstr) {
        const float *x, *W0, *W1; float *t1, *sl; int r;
        if (row < NN) { r = row;      x = xn + (size_t)r * CNF; W0 = Wn0; W1 = Wn1; t1 = wsf + WS_T1N; sl = wsf + WS_SLINN; }
        else          { r = row - NN; x = xe + (size_t)r * CNF; W0 = We0; W1 = We1; t1 = wsf + WS_T1E; sl = wsf + WS_SLINE; }
        float4 xv = ((const float4*)x)[lane];
        float4 w0 = ((const float4*)W0)[lane];
        float4 w1 = ((const float4*)W1)[lane];
        float d0 = xv.x*w0.x + xv.y*w0.y + xv.z*w0.z + xv.w*w0.w;
        float d1 = xv.x*w1.x + xv.y*w1.y + xv.z*w1.z + xv.w*w1.w;
        #pragma unroll
        for (int o = 32; o > 0; o >>= 1) { d0 += __shfl_down(d0, o, 64); d1 += __shfl_down(d1, o, 64); }
        if (lane == 0) { t1[r] = d1; sl[r] = d0 + d1; }
    }
}

// =====================================================================
// Kernel B: conv-edge scatter, grid-wide (single-CU version cost ~200us).
// =====================================================================
__global__ void k_agg(const int* __restrict__ ein, const float* __restrict__ ewn,
                      const int* __restrict__ eie, const float* __restrict__ ewe,
                      float* __restrict__ wsf) {
    int i = blockIdx.x * blockDim.x + threadIdx.x;
    if (i < MN) {
        int s = ein[i], d = ein[MN + i];
        atomicAdd(wsf + WS_AGGN + d, ewn[i] * wsf[WS_T1N + s]);
    }
    if (i < ME) {
        int s = eie[i], d = eie[ME + i];
        atomicAdd(wsf + WS_AGGE + d, ewe[i] * wsf[WS_T1E + s]);
    }
}

// --------------------------------------------------- block reduce (16 waves)
__device__ __forceinline__ float block_reduce_sum(float val, float* red) {
    #pragma unroll
    for (int o = 32; o > 0; o >>= 1) val += __shfl_down(val, o, 64);
    int lane = threadIdx.x & 63, wid = threadIdx.x >> 6;
    if (lane == 0) red[wid] = val;
    __syncthreads();
    float r = 0.0f;
    if (threadIdx.x < 16) {
        r = red[threadIdx.x];
        #pragma unroll
        for (int o = 8; o > 0; o >>= 1) r += __shfl_down(r, o, 16);
        if (threadIdx.x == 0) red[0] = r;
    }
    __syncthreads();
    float out = red[0];
    __syncthreads();
    return out;
}

// =====================================================================
// Kernel C: block 0 = serial chain P3..P9, fully LDS-resident;
// blocks 1..255 zero L0+L1+PM (306 MB, nontemporal) meanwhile.
// R8 lesson: flag-fused epilogue REGRESSED (+24us) — launch boundary
// to k_final is cheaper than agent-scope polling. Keep R7 shape.
// =====================================================================
__global__ __launch_bounds__(1024) void k_mid(
        const int* __restrict__ ei,
        const float* __restrict__ bn, const float* __restrict__ be,
        float* __restrict__ out, float* __restrict__ wsf, int* __restrict__ wsi) {
    int tid = threadIdx.x;
    if (blockIdx.x != 0) {
        // ------------- zeroers: L1, PM, L0 (nontemporal: no reuse pre-k_final) -------------
        size_t w = (size_t)(blockIdx.x - 1) * 1024 + tid;
        size_t ws = (size_t)(gridDim.x - 1) * 1024;
        vf4 z = (vf4)(0.0f);
        vf4* l1 = (vf4*)(out + OUT_L1);
        for (size_t p = w; p < (size_t)EE * EE / 4; p += ws) __builtin_nontemporal_store(z, &l1[p]);
        vf4* pm = (vf4*)(out + OUT_PM);
        for (size_t p = w; p < (size_t)KK * EE / 4; p += ws) __builtin_nontemporal_store(z, &pm[p]);
        vf4* l0 = (vf4*)(out + OUT_L0);
        for (size_t p = w; p < (size_t)KK * KK / 4; p += ws) __builtin_nontemporal_store(z, &l0[p]);
        return;
    }
    // ---------------- block 0: serial chain, LDS-resident ----------------
    __shared__ unsigned long long s_u64[2048];       // 16 KB: sort / deg+scan+cur / power v
    __shared__ float s_joint[2048];                  // 8 KB
    __shared__ unsigned short s_rank[2048];          // 4 KB
    __shared__ unsigned short s_adjo[16384 + DCAP];  // 32 KB (+pad for reg-preload)
    __shared__ float s_red[16];
    int* s_i = (int*)s_u64;                          // 4096 ints, phase-aliased

    // P3: sigmoid scores (AGG filled by k_agg); joint -> LDS, scores -> global
    float bnv = bn[0], bev = be[0];
    for (int i = tid; i < NN; i += 1024) {
        float zv = wsf[WS_SLINN + i] - wsf[WS_AGGN + i] + bnv;
        float s = 1.0f / (1.0f + expf(-zv));
        wsf[WS_SCN + i] = s;
        s_joint[i] = s;
    }
    for (int j = tid; j < EE; j += 1024) {
        float zv = wsf[WS_SLINE + j] - wsf[WS_AGGE + j] + bev;
        wsf[WS_SCE + j] = 1.0f / (1.0f + expf(-zv));
    }
    __syncthreads();

    // P4: joint node score (LDS float atomics; ei read sequentially)
    for (int e = tid; e < EE; e += 1024) {
        float v = 0.125f * wsf[WS_SCE + e];
        atomicAdd(&s_joint[ei[e]], v);
        atomicAdd(&s_joint[ei[EE + e]], v);
    }
    __syncthreads();

    // P5: top-K: bitonic sort 2048 (val,idx) u64 desc, then flag+scan ranks
    for (int i = tid; i < 2048; i += 1024) {
        float f = s_joint[i];
        unsigned u = __float_as_uint(f);
        unsigned sk = (u & 0x80000000u) ? ~u : (u | 0x80000000u);
        s_u64[i] = (((unsigned long long)(~sk)) << 32) | (unsigned)i;
    }
    __syncthreads();
    for (int k = 2; k <= 2048; k <<= 1) {
        for (int j = k >> 1; j >= 1; j >>= 1) {
            for (int i = tid; i < 2048; i += 1024) {
                int ixj = i ^ j;
                if (ixj > i) {
                    bool up = ((i & k) == 0);
                    unsigned long long a = s_u64[i], b = s_u64[ixj];
                    if ((a > b) == up) { s_u64[i] = b; s_u64[ixj] = a; }
                }
            }
            __syncthreads();
        }
    }
    int myid = (int)(s_u64[tid] & 0xFFFFFFFFu);   // top-1024 ids
    __syncthreads();
    {
        s_i[tid] = 0; s_i[tid + 1024] = 0; s_i[tid + 2048] = 0;
        __syncthreads();
        s_i[myid] = 1;                             // kept flags [0,2048)
        __syncthreads();
        int a0 = s_i[2 * tid], a1 = s_i[2 * tid + 1];
        int pairsum = a0 + a1;
        s_i[2048 + tid] = pairsum;
        __syncthreads();
        for (int off = 1; off < 1024; off <<= 1) {
            int v = (tid >= off) ? s_i[2048 + tid - off] : 0;
            __syncthreads();
            s_i[2048 + tid] += v;
            __syncthreads();
        }
        int excl = s_i[2048 + tid] - pairsum;
        int i0 = 2 * tid, i1 = 2 * tid + 1;
        int r0 = excl, r1 = excl + a0;
        s_rank[i0] = a0 ? (unsigned short)r0 : (unsigned short)RBAD;
        s_rank[i1] = a1 ? (unsigned short)r1 : (unsigned short)RBAD;
        wsi[WS_RANK + i0] = a0 ? r0 : -1;          // for k_final
        wsi[WS_RANK + i1] = a1 ? r1 : -1;
        if (a0) wsi[WS_IDXK + r0] = i0;
        if (a1) wsi[WS_IDXK + r1] = i1;
    }
    __syncthreads();

    // P6: degrees (LDS s_i[0..1023]) + keep_e flags (seq global write)
    s_i[tid] = 0;
    __syncthreads();
    for (int e = tid; e < EE; e += 1024) {
        int s = ei[e], d = ei[EE + e];
        unsigned rs = s_rank[s], rd = s_rank[d];
        int kept = (rs != RBAD && rd != RBAD);
        wsi[WS_KEEPE + e] = kept;
        if (kept && s != d) {
            atomicAdd(&s_i[(int)rs], 1);
            atomicAdd(&s_i[(int)rd], 1);
        }
    }
    __syncthreads();

    // P7: CSR offsets: scan deg (s_i[0..1023]) into s_i[1024..2047]; cur in s_i[2048..3071]
    {
        int dg = s_i[tid];
        s_i[1024 + tid] = dg;
        for (int off = 1; off < 1024; off <<= 1) {
            __syncthreads();
            int v = (tid >= off) ? s_i[1024 + tid - off] : 0;
            __syncthreads();
            s_i[1024 + tid] += v;
        }
        __syncthreads();
        int offs = s_i[1024 + tid] - dg;
        s_i[2048 + tid] = offs;                    // cur
        wsi[WS_OFFS + tid] = offs;                 // for k_final + power
        if (tid == 1023) wsi[WS_OFFS + 1024] = s_i[1024 + 1023];
    }
    __syncthreads();

    // P8: CSR fill: adjo -> LDS u16 (power), adje -> global (k_final only)
    for (int e = tid; e < EE; e += 1024) {
        int s = ei[e], d = ei[EE + e];
        unsigned rs = s_rank[s], rd = s_rank[d];
        if (rs != RBAD && rd != RBAD && s != d) {
            int p = atomicAdd(&s_i[2048 + (int)rs], 1);
            s_adjo[p] = (unsigned short)rd;
            wsi[WS_ADJE + p] = (e << 1);
            int q = atomicAdd(&s_i[2048 + (int)rd], 1);
            s_adjo[q] = (unsigned short)rs;
            wsi[WS_ADJE + q] = (e << 1) | 1;
        }
    }
    __syncthreads();

    // P9: power iteration for lambda_max (v aliases s_i[0..2047] as floats;
    // offs read from GLOBAL before v-init to avoid alias hazard)
    {
        int o0 = wsi[WS_OFFS + tid];
        int d  = wsi[WS_OFFS + tid + 1] - o0;
        __syncthreads();
        float* v0 = (float*)s_u64;
        float* v1 = v0 + 1024;
        unsigned h = (unsigned)tid * 2654435761u + 911u;
        h ^= h >> 15; h *= 2246822519u; h ^= h >> 13;
        v0[tid] = (float)(h & 0xFFFFu) * (1.0f / 65536.0f) - 0.5f;
        int aj[DCAP];
        #pragma unroll
        for (int j = 0; j < DCAP; ++j) aj[j] = (j < d) ? (int)s_adjo[o0 + j] : 0;
        __syncthreads();
        float* vc = v0; float* vn = v1;
        for (int iter = 0; iter < PWR_T; ++iter) {
            float acc = 0.0f;
            #pragma unroll
            for (int j = 0; j < DCAP; ++j) acc += (j < d) ? vc[aj[j]] : 0.0f;
            for (int i = o0 + DCAP; i < o0 + d; ++i) acc += vc[(int)s_adjo[i]];
            float y = (float)d * vc[tid] - acc;
            if ((iter & 7) == 7) {
                float n2 = block_reduce_sum(y * y, s_red);
                y *= (n2 > 0.0f) ? rsqrtf(n2) : 0.0f;
            }
            vn[tid] = y;
            __syncthreads();
            float* tmp = vc; vc = vn; vn = tmp;
        }
        float acc = 0.0f;
        #pragma unroll
        for (int j = 0; j < DCAP; ++j) acc += (j < d) ? vc[aj[j]] : 0.0f;
        for (int i = o0 + DCAP; i < o0 + d; ++i) acc += vc[(int)s_adjo[i]];
        float y = (float)d * vc[tid] - acc;
        float rq = block_reduce_sum(vc[tid] * y, s_red);
        if (tid == 0) wsf[WS_LAM] = rq;
    }
}

// =====================================================================
// Kernel D: all output writes that depend on the chain (2/lam folded).
// =====================================================================
__global__ __launch_bounds__(1024) void k_final(
        const float* __restrict__ xn, const float* __restrict__ xe,
        const float* __restrict__ xn0, const float* __restrict__ xe0,
        const int* __restrict__ ei,
        float* __restrict__ out, const float* __restrict__ wsf,
        const int* __restrict__ wsi) {
    float sc = 2.0f / wsf[WS_LAM];
    int gt = blockIdx.x * 1024 + threadIdx.x;
    int gstr = gridDim.x * 1024;

    // (a) kept-node feature gathers (rows fully overwritten, no pre-zero)
    for (int i = gt; i < KK * 64; i += gstr) {
        int r = i >> 6, c = i & 63;
        int src = wsi[WS_IDXK + r];
        float s = wsf[WS_SCN + src];
        float4 v = ((const float4*)(xn + (size_t)src * CNF))[c];
        v.x *= s; v.y *= s; v.z *= s; v.w *= s;
        ((float4*)(out + OUT_XN))[(size_t)r * 64 + c] = v;
        ((float4*)(out + OUT_XN0))[(size_t)r * 64 + c] = ((const float4*)(xn0 + (size_t)src * CNF))[c];
    }
    // (b) edge feature rows, written densely (kept: scaled; dropped: x*0)
    for (int i = gt; i < EE * 64; i += gstr) {
        int e = i >> 6, c = i & 63;
        float m = wsi[WS_KEEPE + e] ? 1.0f : 0.0f;
        float s = m * wsf[WS_SCE + e];
        float4 v = ((const float4*)(xe + (size_t)e * CNF))[c];
        v.x *= s; v.y *= s; v.z *= s; v.w *= s;
        ((float4*)(out + OUT_XE))[(size_t)e * 64 + c] = v;
        float4 v0 = ((const float4*)(xe0 + (size_t)e * CNF))[c];
        v0.x *= m; v0.y *= m; v0.z *= m; v0.w *= m;
        ((float4*)(out + OUT_XE0))[(size_t)e * 64 + c] = v0;
    }
    // (c) par_masked + L0 scatter (pre-zeroed in k_mid)
    {
        float* pm = out + OUT_PM;
        float* L0 = out + OUT_L0;
        for (int e = gt; e < EE; e += gstr) {
            int s = ei[e], d = ei[EE + e];
            int rs = wsi[WS_RANK + s], rd = wsi[WS_RANK + d];
            if (rs < 0 || rd < 0 || s == d) continue;
            pm[(size_t)rs * EE + e] = -1.0f;
            pm[(size_t)rd * EE + e] =  1.0f;
            atomicAdd(&L0[(size_t)rs * KK + rs],  sc);
            atomicAdd(&L0[(size_t)rd * KK + rd],  sc);
            atomicAdd(&L0[(size_t)rs * KK + rd], -sc);
            atomicAdd(&L0[(size_t)rd * KK + rs], -sc);
        }
    }
    // (d) L1 scatter: wave per node-row, lanes over inner pairs
    {
        float* L1 = out + OUT_L1;
        int gwv = gt >> 6, lane = gt & 63, wstr = gstr >> 6;
        for (int r = gwv; r < KK; r += wstr) {
            int o0 = wsi[WS_OFFS + r], o1 = wsi[WS_OFFS + r + 1];
            for (int i = o0; i < o1; ++i) {
                int eiv = wsi[WS_ADJE + i];
                int e = eiv >> 1;
                float si = (eiv & 1) ? sc : -sc;
                for (int j = o0 + lane; j < o1; j += 64) {
                    int ejv = wsi[WS_ADJE + j];
                    atomicAdd(&L1[(size_t)e * EE + (ejv >> 1)], (ejv & 1) ? si : -si);
                }
            }
        }
    }
}

extern "C" void kernel_launch(void* const* d_in, const int* in_sizes, int n_in,
                              void* d_out, int out_size, void* d_ws, size_t ws_size,
                              hipStream_t stream) {
    const float* x_n  = (const float*)d_in[0];
    const int*   ei_n = (const int*)  d_in[1];
    const float* ew_n = (const float*)d_in[2];
    const float* x_e  = (const float*)d_in[3];
    const int*   ei_e = (const int*)  d_in[4];
    const float* ew_e = (const float*)d_in[5];
    const int*   ei   = (const int*)  d_in[6];
    const float* x_n0 = (const float*)d_in[9];
    const float* x_e0 = (const float*)d_in[10];
    const float* Wn0  = (const float*)d_in[11];
    const float* Wn1  = (const float*)d_in[12];
    const float* bn   = (const float*)d_in[13];
    const float* We0  = (const float*)d_in[14];
    const float* We1  = (const float*)d_in[15];
    const float* be   = (const float*)d_in[16];

    float* out = (float*)d_out;
    float* wsf = (float*)d_ws;
    int*   wsi = (int*)d_ws;

    k_prep <<<640, 256, 0, stream>>>(x_n, x_e, Wn0, Wn1, We0, We1, wsf);
    k_agg  <<<256, 256, 0, stream>>>(ei_n, ew_n, ei_e, ew_e, wsf);
    k_mid  <<<256, 1024, 0, stream>>>(ei, bn, be, out, wsf, wsi);
    k_final<<<256, 1024, 0, stream>>>(x_n, x_e, x_n0, x_e0, ei, out, wsf, wsi);
}